// Round 1
// baseline (2437.143 us; speedup 1.0000x reference)
//
#include <hip/hip_runtime.h>
#include <hip/hip_bf16.h>

typedef __bf16 bf16x8 __attribute__((ext_vector_type(8)));
typedef float f32x4 __attribute__((ext_vector_type(4)));

__device__ __forceinline__ float bf2f(unsigned short b) {
  unsigned int u = ((unsigned int)b) << 16;
  return __builtin_bit_cast(float, u);
}
__device__ __forceinline__ unsigned short f2bf(float f) {
  unsigned int u = __builtin_bit_cast(unsigned int, f);
  unsigned int r = u + 0x7fffu + ((u >> 16) & 1u);
  return (unsigned short)(r >> 16);
}

// ---------------- weight conversion ----------------
__global__ void cvt_f32_bf16(const float* __restrict__ in, unsigned short* __restrict__ out, int n) {
  int i = (blockIdx.x * blockDim.x + threadIdx.x) * 4;
  if (i >= n) return;
  float4 v = *(const float4*)(in + i);
  ushort4 o;
  o.x = f2bf(v.x); o.y = f2bf(v.y); o.z = f2bf(v.z); o.w = f2bf(v.w);
  *(ushort4*)(out + i) = o;
}

// pad r_fc3_w (68x256) -> 128x256 bf16, bias -> 128 floats
__global__ void pad_fc3(const float* __restrict__ w, const float* __restrict__ b,
                        unsigned short* __restrict__ wpad, float* __restrict__ bpad) {
  int i = blockIdx.x * 256 + threadIdx.x;  // 0..32767
  int r = i >> 8, c = i & 255;
  wpad[i] = (r < 68) ? f2bf(w[r * 256 + c]) : (unsigned short)0;
  if (i < 128) bpad[i] = (i < 68) ? b[i] : 0.f;
}

// ---------------- GEMM: Out[m, n] = A[m, :256] . W[n, :256] + bias[n] ----------------
// A: row-major, lda elems (fp32 if AF32 else bf16). W: N x 256 bf16 row-major.
// Out: bf16, ldo elems. grid = (M/128, Ncols/128), block = 256.
template <bool AF32>
__global__ __launch_bounds__(256) void gemm_bt(
    const void* __restrict__ Aptr, int lda,
    const unsigned short* __restrict__ W,
    const float* __restrict__ bias,
    unsigned short* __restrict__ Out, int ldo) {
  __shared__ unsigned short As[128][40];
  __shared__ unsigned short Bs[128][40];
  const int tid = threadIdx.x;
  const int lane = tid & 63;
  const int wid = tid >> 6;
  const long row0 = (long)blockIdx.x * 128;
  const int col0 = blockIdx.y * 128;
  const int wr = (wid >> 1) * 64;
  const int wc = (wid & 1) * 64;
  const int srow = tid >> 1;
  const int scol = (tid & 1) * 16;
  const int kf = (lane >> 4) * 8;
  const int rr = lane & 15;
  f32x4 acc[4][4] = {};
  for (int k0 = 0; k0 < 256; k0 += 32) {
    __align__(16) unsigned short abuf[16];
    if (AF32) {
      const float* A = (const float*)Aptr + (row0 + srow) * lda + k0 + scol;
      #pragma unroll
      for (int c = 0; c < 4; c++) {
        float4 v = *(const float4*)(A + c * 4);
        abuf[c * 4 + 0] = f2bf(v.x); abuf[c * 4 + 1] = f2bf(v.y);
        abuf[c * 4 + 2] = f2bf(v.z); abuf[c * 4 + 3] = f2bf(v.w);
      }
    } else {
      const unsigned short* A = (const unsigned short*)Aptr + (row0 + srow) * lda + k0 + scol;
      *(uint4*)(abuf) = *(const uint4*)A;
      *(uint4*)(abuf + 8) = *(const uint4*)(A + 8);
    }
    uint4 b0 = *(const uint4*)&W[(col0 + srow) * 256 + k0 + scol];
    uint4 b1 = *(const uint4*)&W[(col0 + srow) * 256 + k0 + scol + 8];
    __syncthreads();
    *(uint4*)&As[srow][scol] = *(uint4*)abuf;
    *(uint4*)&As[srow][scol + 8] = *(uint4*)(abuf + 8);
    *(uint4*)&Bs[srow][scol] = b0;
    *(uint4*)&Bs[srow][scol + 8] = b1;
    __syncthreads();
    bf16x8 af[4], bfr[4];
    #pragma unroll
    for (int mi = 0; mi < 4; mi++)
      af[mi] = __builtin_bit_cast(bf16x8, *(const uint4*)&As[wr + mi * 16 + rr][kf]);
    #pragma unroll
    for (int ni = 0; ni < 4; ni++)
      bfr[ni] = __builtin_bit_cast(bf16x8, *(const uint4*)&Bs[wc + ni * 16 + rr][kf]);
    #pragma unroll
    for (int mi = 0; mi < 4; mi++)
      #pragma unroll
      for (int ni = 0; ni < 4; ni++)
        acc[mi][ni] = __builtin_amdgcn_mfma_f32_16x16x32_bf16(af[mi], bfr[ni], acc[mi][ni], 0, 0, 0);
  }
  #pragma unroll
  for (int mi = 0; mi < 4; mi++) {
    const int rbase = wr + mi * 16 + (lane >> 4) * 4;
    #pragma unroll
    for (int ni = 0; ni < 4; ni++) {
      const int c_ = wc + ni * 16 + (lane & 15);
      const float bv = bias[col0 + c_];
      #pragma unroll
      for (int r = 0; r < 4; r++) {
        Out[(row0 + rbase + r) * (long)ldo + col0 + c_] = f2bf(acc[mi][ni][r] + bv);
      }
    }
  }
}

// ---------------- depthwise 3x3 + bias + exact GELU (both branches, 512 ch) ----------------
__global__ __launch_bounds__(256) void dwconv_gelu(
    const unsigned short* __restrict__ In,
    const float* __restrict__ Wc, const float* __restrict__ Bc,
    const float* __restrict__ Wr, const float* __restrict__ Br,
    unsigned short* __restrict__ Out) {
  int t = blockIdx.x * 256 + threadIdx.x;  // 131072 * 64
  int g = t & 63;
  int m = t >> 6;
  int n = m >> 12;
  int h = (m >> 6) & 63;
  int w = m & 63;
  int cbase = g << 3;
  int cc = cbase & 255;
  const float* Wt = (cbase < 256) ? Wc : Wr;
  const float* Bt = (cbase < 256) ? Bc : Br;
  float acc[8];
  #pragma unroll
  for (int j = 0; j < 8; j++) acc[j] = Bt[cc + j];
  #pragma unroll
  for (int dy = -1; dy <= 1; dy++) {
    int hh = h + dy;
    if (hh < 0 || hh > 63) continue;
    #pragma unroll
    for (int dx = -1; dx <= 1; dx++) {
      int ww = w + dx;
      if (ww < 0 || ww > 63) continue;
      const unsigned short* src = In + (((long)((n << 6) + hh) << 6) + ww) * 512 + cbase;
      uint4 v = *(const uint4*)src;
      unsigned int u[4] = {v.x, v.y, v.z, v.w};
      int tap = (dy + 1) * 3 + (dx + 1);
      #pragma unroll
      for (int q = 0; q < 4; q++) {
        float lo = bf2f((unsigned short)(u[q] & 0xffffu));
        float hi = bf2f((unsigned short)(u[q] >> 16));
        acc[2 * q]     += lo * Wt[(cc + 2 * q) * 9 + tap];
        acc[2 * q + 1] += hi * Wt[(cc + 2 * q + 1) * 9 + tap];
      }
    }
  }
  __align__(16) unsigned short ov[8];
  #pragma unroll
  for (int j = 0; j < 8; j++) {
    float v = acc[j];
    float ge = 0.5f * v * (1.0f + erff(v * 0.70710678118654752440f));
    ov[j] = f2bf(ge);
  }
  *(uint4*)(Out + (long)m * 512 + cbase) = *(uint4*)ov;
}

// ---------------- cls fc3: dot(G2_c[m,:], w) + b ----------------
__global__ __launch_bounds__(256) void cls_dot(
    const unsigned short* __restrict__ G2,
    const unsigned short* __restrict__ Wc3,
    const float* __restrict__ bc3,
    float* __restrict__ cls_logit) {
  int lane = threadIdx.x & 63;
  int wid = threadIdx.x >> 6;
  long m = (long)blockIdx.x * 4 + wid;
  const unsigned short* row = G2 + m * 512;
  ushort4 a = *(const ushort4*)(row + lane * 4);
  ushort4 wv = *(const ushort4*)(Wc3 + lane * 4);
  float s = bf2f(a.x) * bf2f(wv.x) + bf2f(a.y) * bf2f(wv.y) +
            bf2f(a.z) * bf2f(wv.z) + bf2f(a.w) * bf2f(wv.w);
  #pragma unroll
  for (int off = 32; off > 0; off >>= 1) s += __shfl_down(s, off);
  if (lane == 0) cls_logit[m] = s + bc3[0];
}

// ---------------- post: softmax-17, boxes, top4, q-net, cls fuse ----------------
__global__ __launch_bounds__(256) void post_kernel(
    const unsigned short* __restrict__ RP,
    const float* __restrict__ cls_logit,
    const float* __restrict__ rc1_w, const float* __restrict__ rc1_b,
    const float* __restrict__ rc2_w, const float* __restrict__ rc2_b,
    float* __restrict__ out_cls, float* __restrict__ out_boxes, float* __restrict__ out_reg) {
  int m = blockIdx.x * 256 + threadIdx.x;
  const unsigned short* rp = RP + (long)m * 128;
  float stat[20];
  #pragma unroll
  for (int s = 0; s < 4; s++) {
    float v[17];
    float mx = -1e30f;
    #pragma unroll
    for (int i = 0; i < 17; i++) {
      v[i] = bf2f(rp[s * 17 + i]);
      out_reg[(long)m * 68 + s * 17 + i] = v[i];
      mx = fmaxf(mx, v[i]);
    }
    float sum = 0.f;
    #pragma unroll
    for (int i = 0; i < 17; i++) { v[i] = __expf(v[i] - mx); sum += v[i]; }
    float inv = 1.f / sum;
    float dist = 0.f;
    #pragma unroll
    for (int i = 0; i < 17; i++) { v[i] *= inv; dist += v[i] * (float)i; }
    out_boxes[(long)m * 4 + s] = dist * 0.0625f;
    float tk[4];
    #pragma unroll
    for (int t = 0; t < 4; t++) {
      float bm = v[0]; int bi = 0;
      #pragma unroll
      for (int i = 1; i < 17; i++) {
        if (v[i] > bm) { bm = v[i]; bi = i; }
      }
      tk[t] = bm;
      #pragma unroll
      for (int i = 0; i < 17; i++)
        if (i == bi) v[i] = -1.f;
    }
    stat[s * 5 + 0] = tk[0]; stat[s * 5 + 1] = tk[1];
    stat[s * 5 + 2] = tk[2]; stat[s * 5 + 3] = tk[3];
    stat[s * 5 + 4] = 0.25f * (tk[0] + tk[1] + tk[2] + tk[3]);
  }
  float z = 0.f;
  #pragma unroll
  for (int o = 0; o < 64; o++) {
    float q = rc1_b[o];
    #pragma unroll
    for (int c = 0; c < 20; c++) q += rc1_w[o * 20 + c] * stat[c];
    q = fmaxf(q, 0.f);
    z += q * rc2_w[o];
  }
  z += rc2_b[0];
  float q2 = 1.f / (1.f + __expf(-z));
  float cl = 1.f / (1.f + __expf(-cls_logit[m]));
  out_cls[m] = cl * q2;
}

extern "C" void kernel_launch(void* const* d_in, const int* in_sizes, int n_in,
                              void* d_out, int out_size, void* d_ws, size_t ws_size,
                              hipStream_t stream) {
  const float* x       = (const float*)d_in[0];
  const float* c_fc1_w = (const float*)d_in[1];
  const float* c_fc1_b = (const float*)d_in[2];
  const float* c_dw1_w = (const float*)d_in[3];
  const float* c_dw1_b = (const float*)d_in[4];
  const float* c_fc2_w = (const float*)d_in[5];
  const float* c_fc2_b = (const float*)d_in[6];
  const float* c_dw2_w = (const float*)d_in[7];
  const float* c_dw2_b = (const float*)d_in[8];
  const float* c_fc3_w = (const float*)d_in[9];
  const float* c_fc3_b = (const float*)d_in[10];
  const float* r_fc1_w = (const float*)d_in[11];
  const float* r_fc1_b = (const float*)d_in[12];
  const float* r_dw1_w = (const float*)d_in[13];
  const float* r_dw1_b = (const float*)d_in[14];
  const float* r_fc2_w = (const float*)d_in[15];
  const float* r_fc2_b = (const float*)d_in[16];
  const float* r_dw2_w = (const float*)d_in[17];
  const float* r_dw2_b = (const float*)d_in[18];
  const float* r_fc3_w = (const float*)d_in[19];
  const float* r_fc3_b = (const float*)d_in[20];
  const float* rc1_w   = (const float*)d_in[21];
  const float* rc1_b   = (const float*)d_in[22];
  const float* rc2_w   = (const float*)d_in[23];
  const float* rc2_b   = (const float*)d_in[24];

  const long M = 131072;
  char* ws = (char*)d_ws;
  unsigned short* Hbuf = (unsigned short*)ws;                       // M*512 bf16 = 128 MB
  unsigned short* Gbuf = (unsigned short*)(ws + 134217728L);        // M*512 bf16 = 128 MB
  unsigned short* RP   = (unsigned short*)(ws + 268435456L);        // M*128 bf16 = 32 MB
  float* cls_logit     = (float*)(ws + 268435456L + 33554432L);     // M fp32
  char* wb             = ws + 268435456L + 33554432L + 524288L;
  unsigned short* c_fc1_wb = (unsigned short*)wb;
  unsigned short* r_fc1_wb = c_fc1_wb + 65536;
  unsigned short* c_fc2_wb = r_fc1_wb + 65536;
  unsigned short* r_fc2_wb = c_fc2_wb + 65536;
  unsigned short* c_fc3_wb = r_fc2_wb + 65536;
  unsigned short* wr3_pad  = c_fc3_wb + 256;     // 128*256
  float* bias_pad          = (float*)(wr3_pad + 32768);

  cvt_f32_bf16<<<64, 256, 0, stream>>>(c_fc1_w, c_fc1_wb, 65536);
  cvt_f32_bf16<<<64, 256, 0, stream>>>(r_fc1_w, r_fc1_wb, 65536);
  cvt_f32_bf16<<<64, 256, 0, stream>>>(c_fc2_w, c_fc2_wb, 65536);
  cvt_f32_bf16<<<64, 256, 0, stream>>>(r_fc2_w, r_fc2_wb, 65536);
  cvt_f32_bf16<<<1, 64, 0, stream>>>(c_fc3_w, c_fc3_wb, 256);
  pad_fc3<<<128, 256, 0, stream>>>(r_fc3_w, r_fc3_b, wr3_pad, bias_pad);

  dim3 g2(1024, 2);
  // fc1 (A = x, fp32 converted on the fly)
  gemm_bt<true><<<g2, 256, 0, stream>>>(x, 256, c_fc1_wb, c_fc1_b, Hbuf, 512);
  gemm_bt<true><<<g2, 256, 0, stream>>>(x, 256, r_fc1_wb, r_fc1_b, Hbuf + 256, 512);
  // dwconv1 + gelu
  dwconv_gelu<<<32768, 256, 0, stream>>>(Hbuf, c_dw1_w, c_dw1_b, r_dw1_w, r_dw1_b, Gbuf);
  // fc2
  gemm_bt<false><<<g2, 256, 0, stream>>>(Gbuf, 512, c_fc2_wb, c_fc2_b, Hbuf, 512);
  gemm_bt<false><<<g2, 256, 0, stream>>>(Gbuf + 256, 512, r_fc2_wb, r_fc2_b, Hbuf + 256, 512);
  // dwconv2 + gelu
  dwconv_gelu<<<32768, 256, 0, stream>>>(Hbuf, c_dw2_w, c_dw2_b, r_dw2_w, r_dw2_b, Gbuf);
  // fc3
  cls_dot<<<32768, 256, 0, stream>>>(Gbuf, c_fc3_wb, c_fc3_b, cls_logit);
  gemm_bt<false><<<dim3(1024, 1), 256, 0, stream>>>(Gbuf + 256, 512, wr3_pad, bias_pad, RP, 128);
  // post
  float* out_cls   = (float*)d_out;
  float* out_boxes = out_cls + 131072;
  float* out_reg   = out_boxes + 524288;
  post_kernel<<<512, 256, 0, stream>>>(RP, cls_logit, rc1_w, rc1_b, rc2_w, rc2_b,
                                       out_cls, out_boxes, out_reg);
}

// Round 2
// 686.132 us; speedup vs baseline: 3.5520x; 3.5520x over previous
//
#include <hip/hip_runtime.h>
#include <hip/hip_bf16.h>

typedef __bf16 bf16x8 __attribute__((ext_vector_type(8)));
typedef float f32x4 __attribute__((ext_vector_type(4)));

__device__ __forceinline__ float bf2f(unsigned short b) {
  unsigned int u = ((unsigned int)b) << 16;
  return __builtin_bit_cast(float, u);
}
__device__ __forceinline__ unsigned short f2bf(float f) {
  unsigned int u = __builtin_bit_cast(unsigned int, f);
  unsigned int r = u + 0x7fffu + ((u >> 16) & 1u);
  return (unsigned short)(r >> 16);
}

// ---------------- weight conversion ----------------
__global__ void cvt_f32_bf16(const float* __restrict__ in, unsigned short* __restrict__ out, int n) {
  int i = (blockIdx.x * blockDim.x + threadIdx.x) * 4;
  if (i >= n) return;
  float4 v = *(const float4*)(in + i);
  ushort4 o;
  o.x = f2bf(v.x); o.y = f2bf(v.y); o.z = f2bf(v.z); o.w = f2bf(v.w);
  *(ushort4*)(out + i) = o;
}

// pad r_fc3_w (68x256) -> 128x256 bf16, bias -> 128 floats
__global__ void pad_fc3(const float* __restrict__ w, const float* __restrict__ b,
                        unsigned short* __restrict__ wpad, float* __restrict__ bpad) {
  int i = blockIdx.x * 256 + threadIdx.x;  // 0..32767
  int r = i >> 8, c = i & 255;
  wpad[i] = (r < 68) ? f2bf(w[r * 256 + c]) : (unsigned short)0;
  if (i < 128) bpad[i] = (i < 68) ? b[i] : 0.f;
}

// transpose dw weights (C,1,3,3) of both branches -> [tap][512] fp32, bias -> [512]
__global__ void prep_dw(const float* __restrict__ wc, const float* __restrict__ bc,
                        const float* __restrict__ wr, const float* __restrict__ br,
                        float* __restrict__ wt, float* __restrict__ bt) {
  int i = blockIdx.x * 256 + threadIdx.x;  // 0..4607
  if (i >= 4608) return;
  int tap = i >> 9;
  int ch = i & 511;
  int cc = ch & 255;
  wt[i] = (ch < 256) ? wc[cc * 9 + tap] : wr[cc * 9 + tap];
  if (i < 512) bt[i] = (i < 256) ? bc[i] : br[i & 255];
}

// ---------------- GEMM: Out[m, n] = A[m, :256] . W[n, :256] + bias[n] ----------------
template <bool AF32>
__global__ __launch_bounds__(256) void gemm_bt(
    const void* __restrict__ Aptr, int lda,
    const unsigned short* __restrict__ W,
    const float* __restrict__ bias,
    unsigned short* __restrict__ Out, int ldo) {
  __shared__ unsigned short As[128][40];
  __shared__ unsigned short Bs[128][40];
  const int tid = threadIdx.x;
  const int lane = tid & 63;
  const int wid = tid >> 6;
  const long row0 = (long)blockIdx.x * 128;
  const int col0 = blockIdx.y * 128;
  const int wr = (wid >> 1) * 64;
  const int wc = (wid & 1) * 64;
  const int srow = tid >> 1;
  const int scol = (tid & 1) * 16;
  const int kf = (lane >> 4) * 8;
  const int rr = lane & 15;
  f32x4 acc[4][4] = {};
  for (int k0 = 0; k0 < 256; k0 += 32) {
    __align__(16) unsigned short abuf[16];
    if (AF32) {
      const float* A = (const float*)Aptr + (row0 + srow) * lda + k0 + scol;
      #pragma unroll
      for (int c = 0; c < 4; c++) {
        float4 v = *(const float4*)(A + c * 4);
        abuf[c * 4 + 0] = f2bf(v.x); abuf[c * 4 + 1] = f2bf(v.y);
        abuf[c * 4 + 2] = f2bf(v.z); abuf[c * 4 + 3] = f2bf(v.w);
      }
    } else {
      const unsigned short* A = (const unsigned short*)Aptr + (row0 + srow) * lda + k0 + scol;
      *(uint4*)(abuf) = *(const uint4*)A;
      *(uint4*)(abuf + 8) = *(const uint4*)(A + 8);
    }
    uint4 b0 = *(const uint4*)&W[(col0 + srow) * 256 + k0 + scol];
    uint4 b1 = *(const uint4*)&W[(col0 + srow) * 256 + k0 + scol + 8];
    __syncthreads();
    *(uint4*)&As[srow][scol] = *(uint4*)abuf;
    *(uint4*)&As[srow][scol + 8] = *(uint4*)(abuf + 8);
    *(uint4*)&Bs[srow][scol] = b0;
    *(uint4*)&Bs[srow][scol + 8] = b1;
    __syncthreads();
    bf16x8 af[4], bfr[4];
    #pragma unroll
    for (int mi = 0; mi < 4; mi++)
      af[mi] = __builtin_bit_cast(bf16x8, *(const uint4*)&As[wr + mi * 16 + rr][kf]);
    #pragma unroll
    for (int ni = 0; ni < 4; ni++)
      bfr[ni] = __builtin_bit_cast(bf16x8, *(const uint4*)&Bs[wc + ni * 16 + rr][kf]);
    #pragma unroll
    for (int mi = 0; mi < 4; mi++)
      #pragma unroll
      for (int ni = 0; ni < 4; ni++)
        acc[mi][ni] = __builtin_amdgcn_mfma_f32_16x16x32_bf16(af[mi], bfr[ni], acc[mi][ni], 0, 0, 0);
  }
  #pragma unroll
  for (int mi = 0; mi < 4; mi++) {
    const int rbase = wr + mi * 16 + (lane >> 4) * 4;
    #pragma unroll
    for (int ni = 0; ni < 4; ni++) {
      const int c_ = wc + ni * 16 + (lane & 15);
      const float bv = bias[col0 + c_];
      #pragma unroll
      for (int r = 0; r < 4; r++) {
        Out[(row0 + rbase + r) * (long)ldo + col0 + c_] = f2bf(acc[mi][ni][r] + bv);
      }
    }
  }
}

// ---------------- depthwise 3x3 + bias + exact GELU (both branches, 512 ch) ----------------
// Wt: [9][512] fp32 channel-contiguous; Bt: [512] fp32.
__global__ __launch_bounds__(256) void dwconv_gelu(
    const unsigned short* __restrict__ In,
    const float* __restrict__ Wt, const float* __restrict__ Bt,
    unsigned short* __restrict__ Out) {
  int t = blockIdx.x * 256 + threadIdx.x;  // 131072 * 64
  int g = t & 63;
  int m = t >> 6;
  int n = m >> 12;
  int h = (m >> 6) & 63;
  int w = m & 63;
  int cbase = g << 3;
  float acc[8];
  {
    float4 b0 = *(const float4*)(Bt + cbase);
    float4 b1 = *(const float4*)(Bt + cbase + 4);
    acc[0] = b0.x; acc[1] = b0.y; acc[2] = b0.z; acc[3] = b0.w;
    acc[4] = b1.x; acc[5] = b1.y; acc[6] = b1.z; acc[7] = b1.w;
  }
  #pragma unroll
  for (int dy = -1; dy <= 1; dy++) {
    int hh = h + dy;
    if (hh < 0 || hh > 63) continue;
    #pragma unroll
    for (int dx = -1; dx <= 1; dx++) {
      int ww = w + dx;
      if (ww < 0 || ww > 63) continue;
      int tap = (dy + 1) * 3 + (dx + 1);
      const float* wrow = Wt + tap * 512 + cbase;
      float4 w0 = *(const float4*)(wrow);
      float4 w1 = *(const float4*)(wrow + 4);
      const unsigned short* src = In + (((long)((n << 6) + hh) << 6) + ww) * 512 + cbase;
      uint4 v = *(const uint4*)src;
      acc[0] += bf2f((unsigned short)(v.x & 0xffffu)) * w0.x;
      acc[1] += bf2f((unsigned short)(v.x >> 16)) * w0.y;
      acc[2] += bf2f((unsigned short)(v.y & 0xffffu)) * w0.z;
      acc[3] += bf2f((unsigned short)(v.y >> 16)) * w0.w;
      acc[4] += bf2f((unsigned short)(v.z & 0xffffu)) * w1.x;
      acc[5] += bf2f((unsigned short)(v.z >> 16)) * w1.y;
      acc[6] += bf2f((unsigned short)(v.w & 0xffffu)) * w1.z;
      acc[7] += bf2f((unsigned short)(v.w >> 16)) * w1.w;
    }
  }
  __align__(16) unsigned short ov[8];
  #pragma unroll
  for (int j = 0; j < 8; j++) {
    float v = acc[j];
    float ge = 0.5f * v * (1.0f + erff(v * 0.70710678118654752440f));
    ov[j] = f2bf(ge);
  }
  *(uint4*)(Out + (long)m * 512 + cbase) = *(uint4*)ov;
}

// ---------------- cls fc3: dot(G2_c[m,:], w) + b ----------------
__global__ __launch_bounds__(256) void cls_dot(
    const unsigned short* __restrict__ G2,
    const unsigned short* __restrict__ Wc3,
    const float* __restrict__ bc3,
    float* __restrict__ cls_logit) {
  int lane = threadIdx.x & 63;
  int wid = threadIdx.x >> 6;
  long m = (long)blockIdx.x * 4 + wid;
  const unsigned short* row = G2 + m * 512;
  ushort4 a = *(const ushort4*)(row + lane * 4);
  ushort4 wv = *(const ushort4*)(Wc3 + lane * 4);
  float s = bf2f(a.x) * bf2f(wv.x) + bf2f(a.y) * bf2f(wv.y) +
            bf2f(a.z) * bf2f(wv.z) + bf2f(a.w) * bf2f(wv.w);
  #pragma unroll
  for (int off = 32; off > 0; off >>= 1) s += __shfl_down(s, off);
  if (lane == 0) cls_logit[m] = s + bc3[0];
}

// ---------------- post: softmax-17, boxes, top4, q-net, cls fuse ----------------
__global__ __launch_bounds__(256) void post_kernel(
    const unsigned short* __restrict__ RP,
    const float* __restrict__ cls_logit,
    const float* __restrict__ rc1_w, const float* __restrict__ rc1_b,
    const float* __restrict__ rc2_w, const float* __restrict__ rc2_b,
    float* __restrict__ out_cls, float* __restrict__ out_boxes, float* __restrict__ out_reg) {
  int m = blockIdx.x * 256 + threadIdx.x;
  const unsigned short* rp = RP + (long)m * 128;
  float stat[20];
  #pragma unroll
  for (int s = 0; s < 4; s++) {
    float v[17];
    float mx = -1e30f;
    #pragma unroll
    for (int i = 0; i < 17; i++) {
      v[i] = bf2f(rp[s * 17 + i]);
      out_reg[(long)m * 68 + s * 17 + i] = v[i];
      mx = fmaxf(mx, v[i]);
    }
    float sum = 0.f;
    #pragma unroll
    for (int i = 0; i < 17; i++) { v[i] = __expf(v[i] - mx); sum += v[i]; }
    float inv = 1.f / sum;
    float dist = 0.f;
    #pragma unroll
    for (int i = 0; i < 17; i++) { v[i] *= inv; dist += v[i] * (float)i; }
    out_boxes[(long)m * 4 + s] = dist * 0.0625f;
    float tk[4];
    #pragma unroll
    for (int t = 0; t < 4; t++) {
      float bm = v[0]; int bi = 0;
      #pragma unroll
      for (int i = 1; i < 17; i++) {
        if (v[i] > bm) { bm = v[i]; bi = i; }
      }
      tk[t] = bm;
      #pragma unroll
      for (int i = 0; i < 17; i++)
        if (i == bi) v[i] = -1.f;
    }
    stat[s * 5 + 0] = tk[0]; stat[s * 5 + 1] = tk[1];
    stat[s * 5 + 2] = tk[2]; stat[s * 5 + 3] = tk[3];
    stat[s * 5 + 4] = 0.25f * (tk[0] + tk[1] + tk[2] + tk[3]);
  }
  float z = 0.f;
  #pragma unroll
  for (int o = 0; o < 64; o++) {
    float q = rc1_b[o];
    #pragma unroll
    for (int c = 0; c < 20; c++) q += rc1_w[o * 20 + c] * stat[c];
    q = fmaxf(q, 0.f);
    z += q * rc2_w[o];
  }
  z += rc2_b[0];
  float q2 = 1.f / (1.f + __expf(-z));
  float cl = 1.f / (1.f + __expf(-cls_logit[m]));
  out_cls[m] = cl * q2;
}

extern "C" void kernel_launch(void* const* d_in, const int* in_sizes, int n_in,
                              void* d_out, int out_size, void* d_ws, size_t ws_size,
                              hipStream_t stream) {
  const float* x       = (const float*)d_in[0];
  const float* c_fc1_w = (const float*)d_in[1];
  const float* c_fc1_b = (const float*)d_in[2];
  const float* c_dw1_w = (const float*)d_in[3];
  const float* c_dw1_b = (const float*)d_in[4];
  const float* c_fc2_w = (const float*)d_in[5];
  const float* c_fc2_b = (const float*)d_in[6];
  const float* c_dw2_w = (const float*)d_in[7];
  const float* c_dw2_b = (const float*)d_in[8];
  const float* c_fc3_w = (const float*)d_in[9];
  const float* c_fc3_b = (const float*)d_in[10];
  const float* r_fc1_w = (const float*)d_in[11];
  const float* r_fc1_b = (const float*)d_in[12];
  const float* r_dw1_w = (const float*)d_in[13];
  const float* r_dw1_b = (const float*)d_in[14];
  const float* r_fc2_w = (const float*)d_in[15];
  const float* r_fc2_b = (const float*)d_in[16];
  const float* r_dw2_w = (const float*)d_in[17];
  const float* r_dw2_b = (const float*)d_in[18];
  const float* r_fc3_w = (const float*)d_in[19];
  const float* r_fc3_b = (const float*)d_in[20];
  const float* rc1_w   = (const float*)d_in[21];
  const float* rc1_b   = (const float*)d_in[22];
  const float* rc2_w   = (const float*)d_in[23];
  const float* rc2_b   = (const float*)d_in[24];

  char* ws = (char*)d_ws;
  unsigned short* Hbuf = (unsigned short*)ws;                       // M*512 bf16 = 128 MB
  unsigned short* Gbuf = (unsigned short*)(ws + 134217728L);        // M*512 bf16 = 128 MB
  unsigned short* RP   = (unsigned short*)(ws + 268435456L);        // M*128 bf16 = 32 MB
  float* cls_logit     = (float*)(ws + 268435456L + 33554432L);     // M fp32
  char* wb             = ws + 268435456L + 33554432L + 524288L;
  unsigned short* c_fc1_wb = (unsigned short*)wb;
  unsigned short* r_fc1_wb = c_fc1_wb + 65536;
  unsigned short* c_fc2_wb = r_fc1_wb + 65536;
  unsigned short* r_fc2_wb = c_fc2_wb + 65536;
  unsigned short* c_fc3_wb = r_fc2_wb + 65536;
  unsigned short* wr3_pad  = c_fc3_wb + 256;     // 128*256
  float* bias_pad          = (float*)(wr3_pad + 32768);   // 128 floats
  float* wdw1 = bias_pad + 128;       // 4608 floats
  float* bdw1 = wdw1 + 4608;          // 512
  float* wdw2 = bdw1 + 512;           // 4608
  float* bdw2 = wdw2 + 4608;          // 512

  cvt_f32_bf16<<<64, 256, 0, stream>>>(c_fc1_w, c_fc1_wb, 65536);
  cvt_f32_bf16<<<64, 256, 0, stream>>>(r_fc1_w, r_fc1_wb, 65536);
  cvt_f32_bf16<<<64, 256, 0, stream>>>(c_fc2_w, c_fc2_wb, 65536);
  cvt_f32_bf16<<<64, 256, 0, stream>>>(r_fc2_w, r_fc2_wb, 65536);
  cvt_f32_bf16<<<1, 64, 0, stream>>>(c_fc3_w, c_fc3_wb, 256);
  pad_fc3<<<128, 256, 0, stream>>>(r_fc3_w, r_fc3_b, wr3_pad, bias_pad);
  prep_dw<<<18, 256, 0, stream>>>(c_dw1_w, c_dw1_b, r_dw1_w, r_dw1_b, wdw1, bdw1);
  prep_dw<<<18, 256, 0, stream>>>(c_dw2_w, c_dw2_b, r_dw2_w, r_dw2_b, wdw2, bdw2);

  dim3 g2(1024, 2);
  // fc1 (A = x, fp32 converted on the fly)
  gemm_bt<true><<<g2, 256, 0, stream>>>(x, 256, c_fc1_wb, c_fc1_b, Hbuf, 512);
  gemm_bt<true><<<g2, 256, 0, stream>>>(x, 256, r_fc1_wb, r_fc1_b, Hbuf + 256, 512);
  // dwconv1 + gelu
  dwconv_gelu<<<32768, 256, 0, stream>>>(Hbuf, wdw1, bdw1, Gbuf);
  // fc2
  gemm_bt<false><<<g2, 256, 0, stream>>>(Gbuf, 512, c_fc2_wb, c_fc2_b, Hbuf, 512);
  gemm_bt<false><<<g2, 256, 0, stream>>>(Gbuf + 256, 512, r_fc2_wb, r_fc2_b, Hbuf + 256, 512);
  // dwconv2 + gelu
  dwconv_gelu<<<32768, 256, 0, stream>>>(Hbuf, wdw2, bdw2, Gbuf);
  // fc3
  cls_dot<<<32768, 256, 0, stream>>>(Gbuf, c_fc3_wb, c_fc3_b, cls_logit);
  gemm_bt<false><<<dim3(1024, 1), 256, 0, stream>>>(Gbuf + 256, 512, wr3_pad, bias_pad, RP, 128);
  // post
  float* out_cls   = (float*)d_out;
  float* out_boxes = out_cls + 131072;
  float* out_reg   = out_boxes + 524288;
  post_kernel<<<512, 256, 0, stream>>>(RP, cls_logit, rc1_w, rc1_b, rc2_w, rc2_b,
                                       out_cls, out_boxes, out_reg);
}

// Round 3
// 587.822 us; speedup vs baseline: 4.1461x; 1.1672x over previous
//
#include <hip/hip_runtime.h>
#include <hip/hip_bf16.h>

typedef __bf16 bf16x8 __attribute__((ext_vector_type(8)));
typedef float f32x4 __attribute__((ext_vector_type(4)));
typedef float f32x2 __attribute__((ext_vector_type(2)));

__device__ __forceinline__ float bf2f(unsigned short b) {
  unsigned int u = ((unsigned int)b) << 16;
  return __builtin_bit_cast(float, u);
}
__device__ __forceinline__ unsigned short f2bf(float f) {
  unsigned int u = __builtin_bit_cast(unsigned int, f);
  unsigned int r = u + 0x7fffu + ((u >> 16) & 1u);
  return (unsigned short)(r >> 16);
}
__device__ __forceinline__ f32x2 unpack2(unsigned int u) {
  f32x2 r;
  r.x = __builtin_bit_cast(float, u << 16);
  r.y = __builtin_bit_cast(float, u & 0xffff0000u);
  return r;
}

// exact-erf GELU on a packed pair (A&S 7.1.26 erfc, |err|<=1.5e-7, branchless)
__device__ __forceinline__ f32x2 gelu2(f32x2 x) {
  f32x2 z = x * 0.70710678118654752440f;
  f32x2 az; az.x = fabsf(z.x); az.y = fabsf(z.y);
  f32x2 t;
  t.x = __builtin_amdgcn_rcpf(__builtin_fmaf(0.3275911f, az.x, 1.0f));
  t.y = __builtin_amdgcn_rcpf(__builtin_fmaf(0.3275911f, az.y, 1.0f));
  f32x2 y = t * (0.254829592f + t * (-0.284496736f + t * (1.421413741f +
            t * (-1.453152027f + t * 1.061405429f))));
  f32x2 zz = z * z;
  f32x2 e; e.x = __expf(-zz.x); e.y = __expf(-zz.y);
  f32x2 ec = y * e;                       // erfc(|z|)
  f32x2 d = 0.5f - 0.5f * ec;             // >= 0
  f32x2 ph;
  ph.x = 0.5f + __builtin_copysignf(d.x, z.x);
  ph.y = 0.5f + __builtin_copysignf(d.y, z.y);
  return x * ph;
}

// ---------------- fused weight prep (one dispatch) ----------------
__global__ __launch_bounds__(256) void prep_all(
    const float* __restrict__ c1w, const float* __restrict__ r1w,
    const float* __restrict__ c2w, const float* __restrict__ r2w,
    const float* __restrict__ c3w, const float* __restrict__ r3w, const float* __restrict__ r3b,
    const float* __restrict__ c1b, const float* __restrict__ r1b,
    const float* __restrict__ c2b, const float* __restrict__ r2b,
    const float* __restrict__ d1wc, const float* __restrict__ d1bc,
    const float* __restrict__ d1wr, const float* __restrict__ d1br,
    const float* __restrict__ d2wc, const float* __restrict__ d2bc,
    const float* __restrict__ d2wr, const float* __restrict__ d2br,
    unsigned short* __restrict__ w1cat, unsigned short* __restrict__ w2cat,
    unsigned short* __restrict__ c3wb, unsigned short* __restrict__ wr3pad,
    float* __restrict__ br3pad, float* __restrict__ b1cat, float* __restrict__ b2cat,
    float* __restrict__ wd1, float* __restrict__ bd1,
    float* __restrict__ wd2, float* __restrict__ bd2) {
  int i = blockIdx.x * 256 + threadIdx.x;  // 262144
  {
    int which = i >> 16, j = i & 65535;
    float v = (which == 0) ? c1w[j] : (which == 1) ? r1w[j] : (which == 2) ? c2w[j] : r2w[j];
    unsigned short* dst = (which < 2) ? (w1cat + which * 65536) : (w2cat + (which - 2) * 65536);
    dst[j] = f2bf(v);
  }
  if (i < 32768) {
    int r = i >> 8, c = i & 255;
    wr3pad[i] = (r < 68) ? f2bf(r3w[r * 256 + c]) : (unsigned short)0;
    if (i < 128) br3pad[i] = (i < 68) ? r3b[i] : 0.f;
  }
  if (i < 256) c3wb[i] = f2bf(c3w[i]);
  if (i < 4608) {
    int tap = i >> 9, ch = i & 511, cc = ch & 255;
    wd1[i] = (ch < 256) ? d1wc[cc * 9 + tap] : d1wr[cc * 9 + tap];
    wd2[i] = (ch < 256) ? d2wc[cc * 9 + tap] : d2wr[cc * 9 + tap];
  }
  if (i < 512) {
    bd1[i] = (i < 256) ? d1bc[i] : d1br[i & 255];
    bd2[i] = (i < 256) ? d2bc[i] : d2br[i & 255];
    b1cat[i] = (i < 256) ? c1b[i] : r1b[i & 255];
    b2cat[i] = (i < 256) ? c2b[i] : r2b[i & 255];
  }
}

// ---------------- GEMM: Out[m, n] = A[m, :256] . W[n, :256] + bias[n] ----------------
// blockIdx.z selects a "branch": per-z element offsets for A/W/bias/Out.
template <bool AF32>
__global__ __launch_bounds__(256) void gemm_bt(
    const void* __restrict__ Aptr, int lda, int zAoff,
    const unsigned short* __restrict__ W, int zWoff,
    const float* __restrict__ bias, int zBoff,
    unsigned short* __restrict__ Out, int ldo, int zOoff) {
  __shared__ unsigned short As[128][40];
  __shared__ unsigned short Bs[128][40];
  const int z = blockIdx.z;
  const unsigned short* Wz = W + (long)z * zWoff;
  const float* biasz = bias + z * zBoff;
  unsigned short* Outz = Out + (long)z * zOoff;
  const int tid = threadIdx.x;
  const int lane = tid & 63;
  const int wid = tid >> 6;
  const long row0 = (long)blockIdx.x * 128;
  const int col0 = blockIdx.y * 128;
  const int wr = (wid >> 1) * 64;
  const int wc = (wid & 1) * 64;
  const int srow = tid >> 1;
  const int scol = (tid & 1) * 16;
  const int kf = (lane >> 4) * 8;
  const int rr = lane & 15;
  f32x4 acc[4][4] = {};
  for (int k0 = 0; k0 < 256; k0 += 32) {
    __align__(16) unsigned short abuf[16];
    if (AF32) {
      const float* A = (const float*)Aptr + (long)z * zAoff + (row0 + srow) * lda + k0 + scol;
      #pragma unroll
      for (int c = 0; c < 4; c++) {
        float4 v = *(const float4*)(A + c * 4);
        abuf[c * 4 + 0] = f2bf(v.x); abuf[c * 4 + 1] = f2bf(v.y);
        abuf[c * 4 + 2] = f2bf(v.z); abuf[c * 4 + 3] = f2bf(v.w);
      }
    } else {
      const unsigned short* A = (const unsigned short*)Aptr + (long)z * zAoff + (row0 + srow) * lda + k0 + scol;
      *(uint4*)(abuf) = *(const uint4*)A;
      *(uint4*)(abuf + 8) = *(const uint4*)(A + 8);
    }
    uint4 b0 = *(const uint4*)&Wz[(col0 + srow) * 256 + k0 + scol];
    uint4 b1 = *(const uint4*)&Wz[(col0 + srow) * 256 + k0 + scol + 8];
    __syncthreads();
    *(uint4*)&As[srow][scol] = *(uint4*)abuf;
    *(uint4*)&As[srow][scol + 8] = *(uint4*)(abuf + 8);
    *(uint4*)&Bs[srow][scol] = b0;
    *(uint4*)&Bs[srow][scol + 8] = b1;
    __syncthreads();
    bf16x8 af[4], bfr[4];
    #pragma unroll
    for (int mi = 0; mi < 4; mi++)
      af[mi] = __builtin_bit_cast(bf16x8, *(const uint4*)&As[wr + mi * 16 + rr][kf]);
    #pragma unroll
    for (int ni = 0; ni < 4; ni++)
      bfr[ni] = __builtin_bit_cast(bf16x8, *(const uint4*)&Bs[wc + ni * 16 + rr][kf]);
    #pragma unroll
    for (int mi = 0; mi < 4; mi++)
      #pragma unroll
      for (int ni = 0; ni < 4; ni++)
        acc[mi][ni] = __builtin_amdgcn_mfma_f32_16x16x32_bf16(af[mi], bfr[ni], acc[mi][ni], 0, 0, 0);
  }
  #pragma unroll
  for (int mi = 0; mi < 4; mi++) {
    const int rbase = wr + mi * 16 + (lane >> 4) * 4;
    #pragma unroll
    for (int ni = 0; ni < 4; ni++) {
      const int c_ = wc + ni * 16 + (lane & 15);
      const float bv = biasz[col0 + c_];
      #pragma unroll
      for (int r = 0; r < 4; r++) {
        Outz[(row0 + rbase + r) * (long)ldo + col0 + c_] = f2bf(acc[mi][ni][r] + bv);
      }
    }
  }
}

// ---------------- depthwise 3x3 + bias + exact GELU, 2 pixels/thread ----------------
// Wt: [9][512] fp32 channel-contiguous; Bt: [512] fp32.
__global__ __launch_bounds__(256) void dwconv_gelu2(
    const unsigned short* __restrict__ In,
    const float* __restrict__ Wt, const float* __restrict__ Bt,
    unsigned short* __restrict__ Out) {
  int t = blockIdx.x * 256 + threadIdx.x;  // 65536 pairs * 64 groups
  int g = t & 63;
  int p = t >> 6;
  int n = p >> 11;
  int h = (p >> 5) & 63;
  int w0 = (p & 31) * 2;
  int cbase = g << 3;
  f32x2 accA[4], accB[4];
  {
    float4 b0 = *(const float4*)(Bt + cbase);
    float4 b1 = *(const float4*)(Bt + cbase + 4);
    accA[0].x = b0.x; accA[0].y = b0.y; accA[1].x = b0.z; accA[1].y = b0.w;
    accA[2].x = b1.x; accA[2].y = b1.y; accA[3].x = b1.z; accA[3].y = b1.w;
    #pragma unroll
    for (int i = 0; i < 4; i++) accB[i] = accA[i];
  }
  #pragma unroll
  for (int dy = -1; dy <= 1; dy++) {
    int hh = h + dy;
    if (hh < 0 || hh > 63) continue;
    const float* wb = Wt + ((dy + 1) * 3) * 512 + cbase;
    f32x2 wt0[4], wt1[4], wt2[4];
    {
      float4 a0 = *(const float4*)(wb);        float4 a1 = *(const float4*)(wb + 4);
      float4 b0 = *(const float4*)(wb + 512);  float4 b1 = *(const float4*)(wb + 516);
      float4 c0 = *(const float4*)(wb + 1024); float4 c1 = *(const float4*)(wb + 1028);
      wt0[0].x = a0.x; wt0[0].y = a0.y; wt0[1].x = a0.z; wt0[1].y = a0.w;
      wt0[2].x = a1.x; wt0[2].y = a1.y; wt0[3].x = a1.z; wt0[3].y = a1.w;
      wt1[0].x = b0.x; wt1[0].y = b0.y; wt1[1].x = b0.z; wt1[1].y = b0.w;
      wt1[2].x = b1.x; wt1[2].y = b1.y; wt1[3].x = b1.z; wt1[3].y = b1.w;
      wt2[0].x = c0.x; wt2[0].y = c0.y; wt2[1].x = c0.z; wt2[1].y = c0.w;
      wt2[2].x = c1.x; wt2[2].y = c1.y; wt2[3].x = c1.z; wt2[3].y = c1.w;
    }
    const long rowtok = (long)(((n << 6) + hh) << 6);
    // col w0-1 -> A tap0
    if (w0 > 0) {
      uint4 v = *(const uint4*)(In + (rowtok + w0 - 1) * 512 + cbase);
      unsigned int u[4] = {v.x, v.y, v.z, v.w};
      #pragma unroll
      for (int i = 0; i < 4; i++) { f32x2 f = unpack2(u[i]); accA[i] += f * wt0[i]; }
    }
    // col w0 -> A tap1, B tap0
    {
      uint4 v = *(const uint4*)(In + (rowtok + w0) * 512 + cbase);
      unsigned int u[4] = {v.x, v.y, v.z, v.w};
      #pragma unroll
      for (int i = 0; i < 4; i++) { f32x2 f = unpack2(u[i]); accA[i] += f * wt1[i]; accB[i] += f * wt0[i]; }
    }
    // col w0+1 -> A tap2, B tap1
    {
      uint4 v = *(const uint4*)(In + (rowtok + w0 + 1) * 512 + cbase);
      unsigned int u[4] = {v.x, v.y, v.z, v.w};
      #pragma unroll
      for (int i = 0; i < 4; i++) { f32x2 f = unpack2(u[i]); accA[i] += f * wt2[i]; accB[i] += f * wt1[i]; }
    }
    // col w0+2 -> B tap2
    if (w0 < 62) {
      uint4 v = *(const uint4*)(In + (rowtok + w0 + 2) * 512 + cbase);
      unsigned int u[4] = {v.x, v.y, v.z, v.w};
      #pragma unroll
      for (int i = 0; i < 4; i++) { f32x2 f = unpack2(u[i]); accB[i] += f * wt2[i]; }
    }
  }
  long mA = (long)(((n << 6) + h) << 6) + w0;
  __align__(16) unsigned short ov[8];
  #pragma unroll
  for (int i = 0; i < 4; i++) {
    f32x2 gA = gelu2(accA[i]);
    ov[2 * i] = f2bf(gA.x); ov[2 * i + 1] = f2bf(gA.y);
  }
  *(uint4*)(Out + mA * 512 + cbase) = *(uint4*)ov;
  #pragma unroll
  for (int i = 0; i < 4; i++) {
    f32x2 gB = gelu2(accB[i]);
    ov[2 * i] = f2bf(gB.x); ov[2 * i + 1] = f2bf(gB.y);
  }
  *(uint4*)(Out + (mA + 1) * 512 + cbase) = *(uint4*)ov;
}

// ---------------- cls fc3: dot(G2_c[m,:], w) + b ----------------
__global__ __launch_bounds__(256) void cls_dot(
    const unsigned short* __restrict__ G2,
    const unsigned short* __restrict__ Wc3,
    const float* __restrict__ bc3,
    float* __restrict__ cls_logit) {
  int lane = threadIdx.x & 63;
  int wid = threadIdx.x >> 6;
  long m = (long)blockIdx.x * 4 + wid;
  const unsigned short* row = G2 + m * 512;
  ushort4 a = *(const ushort4*)(row + lane * 4);
  ushort4 wv = *(const ushort4*)(Wc3 + lane * 4);
  float s = bf2f(a.x) * bf2f(wv.x) + bf2f(a.y) * bf2f(wv.y) +
            bf2f(a.z) * bf2f(wv.z) + bf2f(a.w) * bf2f(wv.w);
  #pragma unroll
  for (int off = 32; off > 0; off >>= 1) s += __shfl_down(s, off);
  if (lane == 0) cls_logit[m] = s + bc3[0];
}

// ---------------- post: softmax-17, boxes, top4, q-net, cls fuse ----------------
__global__ __launch_bounds__(256) void post_kernel(
    const unsigned short* __restrict__ RP,
    const float* __restrict__ cls_logit,
    const float* __restrict__ rc1_w, const float* __restrict__ rc1_b,
    const float* __restrict__ rc2_w, const float* __restrict__ rc2_b,
    float* __restrict__ out_cls, float* __restrict__ out_boxes, float* __restrict__ out_reg) {
  int m = blockIdx.x * 256 + threadIdx.x;
  const unsigned short* rp = RP + (long)m * 128;
  float stat[20];
  #pragma unroll
  for (int s = 0; s < 4; s++) {
    float v[17];
    float mx = -1e30f;
    #pragma unroll
    for (int i = 0; i < 17; i++) {
      v[i] = bf2f(rp[s * 17 + i]);
      out_reg[(long)m * 68 + s * 17 + i] = v[i];
      mx = fmaxf(mx, v[i]);
    }
    float sum = 0.f;
    #pragma unroll
    for (int i = 0; i < 17; i++) { v[i] = __expf(v[i] - mx); sum += v[i]; }
    float inv = 1.f / sum;
    float dist = 0.f;
    #pragma unroll
    for (int i = 0; i < 17; i++) { v[i] *= inv; dist += v[i] * (float)i; }
    out_boxes[(long)m * 4 + s] = dist * 0.0625f;
    float tk[4];
    #pragma unroll
    for (int t = 0; t < 4; t++) {
      float bm = v[0]; int bi = 0;
      #pragma unroll
      for (int i = 1; i < 17; i++) {
        if (v[i] > bm) { bm = v[i]; bi = i; }
      }
      tk[t] = bm;
      #pragma unroll
      for (int i = 0; i < 17; i++)
        if (i == bi) v[i] = -1.f;
    }
    stat[s * 5 + 0] = tk[0]; stat[s * 5 + 1] = tk[1];
    stat[s * 5 + 2] = tk[2]; stat[s * 5 + 3] = tk[3];
    stat[s * 5 + 4] = 0.25f * (tk[0] + tk[1] + tk[2] + tk[3]);
  }
  float z = 0.f;
  #pragma unroll
  for (int o = 0; o < 64; o++) {
    float q = rc1_b[o];
    #pragma unroll
    for (int c = 0; c < 20; c++) q += rc1_w[o * 20 + c] * stat[c];
    q = fmaxf(q, 0.f);
    z += q * rc2_w[o];
  }
  z += rc2_b[0];
  float q2 = 1.f / (1.f + __expf(-z));
  float cl = 1.f / (1.f + __expf(-cls_logit[m]));
  out_cls[m] = cl * q2;
}

extern "C" void kernel_launch(void* const* d_in, const int* in_sizes, int n_in,
                              void* d_out, int out_size, void* d_ws, size_t ws_size,
                              hipStream_t stream) {
  const float* x       = (const float*)d_in[0];
  const float* c_fc1_w = (const float*)d_in[1];
  const float* c_fc1_b = (const float*)d_in[2];
  const float* c_dw1_w = (const float*)d_in[3];
  const float* c_dw1_b = (const float*)d_in[4];
  const float* c_fc2_w = (const float*)d_in[5];
  const float* c_fc2_b = (const float*)d_in[6];
  const float* c_dw2_w = (const float*)d_in[7];
  const float* c_dw2_b = (const float*)d_in[8];
  const float* c_fc3_w = (const float*)d_in[9];
  const float* c_fc3_b = (const float*)d_in[10];
  const float* r_fc1_w = (const float*)d_in[11];
  const float* r_fc1_b = (const float*)d_in[12];
  const float* r_dw1_w = (const float*)d_in[13];
  const float* r_dw1_b = (const float*)d_in[14];
  const float* r_fc2_w = (const float*)d_in[15];
  const float* r_fc2_b = (const float*)d_in[16];
  const float* r_dw2_w = (const float*)d_in[17];
  const float* r_dw2_b = (const float*)d_in[18];
  const float* r_fc3_w = (const float*)d_in[19];
  const float* r_fc3_b = (const float*)d_in[20];
  const float* rc1_w   = (const float*)d_in[21];
  const float* rc1_b   = (const float*)d_in[22];
  const float* rc2_w   = (const float*)d_in[23];
  const float* rc2_b   = (const float*)d_in[24];

  char* ws = (char*)d_ws;
  unsigned short* Hbuf = (unsigned short*)ws;                       // 128 MiB
  unsigned short* Gbuf = (unsigned short*)(ws + 134217728L);        // 128 MiB
  unsigned short* RP   = (unsigned short*)(ws + 268435456L);        // 32 MiB
  float* cls_logit     = (float*)(ws + 301989888L);                 // 512 KiB
  char* wb             = ws + 302514176L;
  unsigned short* w1cat  = (unsigned short*)wb;          // 131072 bf16 (c_fc1|r_fc1)
  unsigned short* w2cat  = w1cat + 131072;               // 131072 bf16 (c_fc2|r_fc2)
  unsigned short* c3wb   = w2cat + 131072;               // 256
  unsigned short* wr3pad = c3wb + 256;                   // 32768
  float* br3pad = (float*)(wr3pad + 32768);              // 128
  float* b1cat  = br3pad + 128;                          // 512
  float* b2cat  = b1cat + 512;                           // 512
  float* wd1    = b2cat + 512;                           // 4608
  float* bd1    = wd1 + 4608;                            // 512
  float* wd2    = bd1 + 512;                             // 4608
  float* bd2    = wd2 + 4608;                            // 512

  prep_all<<<1024, 256, 0, stream>>>(
      c_fc1_w, r_fc1_w, c_fc2_w, r_fc2_w, c_fc3_w, r_fc3_w, r_fc3_b,
      c_fc1_b, r_fc1_b, c_fc2_b, r_fc2_b,
      c_dw1_w, c_dw1_b, r_dw1_w, r_dw1_b,
      c_dw2_w, c_dw2_b, r_dw2_w, r_dw2_b,
      w1cat, w2cat, c3wb, wr3pad, br3pad, b1cat, b2cat,
      wd1, bd1, wd2, bd2);

  // fc1 (A = x fp32, one GEMM over N=512)
  gemm_bt<true><<<dim3(1024, 4, 1), 256, 0, stream>>>(
      x, 256, 0, w1cat, 0, b1cat, 0, Hbuf, 512, 0);
  // dwconv1 + gelu
  dwconv_gelu2<<<16384, 256, 0, stream>>>(Hbuf, wd1, bd1, Gbuf);
  // fc2 (two branches via blockIdx.z)
  gemm_bt<false><<<dim3(1024, 2, 2), 256, 0, stream>>>(
      Gbuf, 512, 256, w2cat, 65536, b2cat, 256, Hbuf, 512, 256);
  // dwconv2 + gelu
  dwconv_gelu2<<<16384, 256, 0, stream>>>(Hbuf, wd2, bd2, Gbuf);
  // fc3
  cls_dot<<<32768, 256, 0, stream>>>(Gbuf, c3wb, c_fc3_b, cls_logit);
  gemm_bt<false><<<dim3(1024, 1, 1), 256, 0, stream>>>(
      Gbuf + 256, 512, 0, wr3pad, 0, br3pad, 0, RP, 128, 0);
  // post
  float* out_cls   = (float*)d_out;
  float* out_boxes = out_cls + 131072;
  float* out_reg   = out_boxes + 524288;
  post_kernel<<<512, 256, 0, stream>>>(RP, cls_logit, rc1_w, rc1_b, rc2_w, rc2_b,
                                       out_cls, out_boxes, out_reg);
}

// Round 4
// 398.448 us; speedup vs baseline: 6.1166x; 1.4753x over previous
//
#include <hip/hip_runtime.h>
#include <hip/hip_bf16.h>

typedef __bf16 bf16x8 __attribute__((ext_vector_type(8)));
typedef float f32x4 __attribute__((ext_vector_type(4)));
typedef float f32x2 __attribute__((ext_vector_type(2)));

__device__ __forceinline__ float bf2f(unsigned short b) {
  unsigned int u = ((unsigned int)b) << 16;
  return __builtin_bit_cast(float, u);
}
__device__ __forceinline__ unsigned short f2bf(float f) {
  unsigned int u = __builtin_bit_cast(unsigned int, f);
  unsigned int r = u + 0x7fffu + ((u >> 16) & 1u);
  return (unsigned short)(r >> 16);
}
__device__ __forceinline__ f32x2 unpack2(unsigned int u) {
  f32x2 r;
  r.x = __builtin_bit_cast(float, u << 16);
  r.y = __builtin_bit_cast(float, u & 0xffff0000u);
  return r;
}

__device__ __forceinline__ void gload16(const void* g, void* l) {
  typedef __attribute__((address_space(1))) const void* gp_t;
  typedef __attribute__((address_space(3))) void* lp_t;
  __builtin_amdgcn_global_load_lds((gp_t)g, (lp_t)l, 16, 0, 0);
}

// exact-erf GELU on a packed pair (A&S 7.1.26 erfc, |err|<=1.5e-7, branchless)
__device__ __forceinline__ f32x2 gelu2(f32x2 x) {
  f32x2 z = x * 0.70710678118654752440f;
  f32x2 az; az.x = fabsf(z.x); az.y = fabsf(z.y);
  f32x2 t;
  t.x = __builtin_amdgcn_rcpf(__builtin_fmaf(0.3275911f, az.x, 1.0f));
  t.y = __builtin_amdgcn_rcpf(__builtin_fmaf(0.3275911f, az.y, 1.0f));
  f32x2 y = t * (0.254829592f + t * (-0.284496736f + t * (1.421413741f +
            t * (-1.453152027f + t * 1.061405429f))));
  f32x2 zz = z * z;
  f32x2 e; e.x = __expf(-zz.x); e.y = __expf(-zz.y);
  f32x2 ec = y * e;                       // erfc(|z|)
  f32x2 d = 0.5f - 0.5f * ec;             // >= 0
  f32x2 ph;
  ph.x = 0.5f + __builtin_copysignf(d.x, z.x);
  ph.y = 0.5f + __builtin_copysignf(d.y, z.y);
  return x * ph;
}

// ---------------- x fp32 -> bf16 ----------------
__global__ __launch_bounds__(256) void cvt_x(const float* __restrict__ in,
                                             unsigned short* __restrict__ out) {
  long i = ((long)blockIdx.x * 256 + threadIdx.x) * 8;
  float4 a = *(const float4*)(in + i);
  float4 b = *(const float4*)(in + i + 4);
  __align__(16) unsigned short o[8];
  o[0] = f2bf(a.x); o[1] = f2bf(a.y); o[2] = f2bf(a.z); o[3] = f2bf(a.w);
  o[4] = f2bf(b.x); o[5] = f2bf(b.y); o[6] = f2bf(b.z); o[7] = f2bf(b.w);
  *(uint4*)(out + i) = *(uint4*)o;
}

// ---------------- fused weight prep (one dispatch) ----------------
__global__ __launch_bounds__(256) void prep_all(
    const float* __restrict__ c1w, const float* __restrict__ r1w,
    const float* __restrict__ c2w, const float* __restrict__ r2w,
    const float* __restrict__ c3w, const float* __restrict__ r3w, const float* __restrict__ r3b,
    const float* __restrict__ c1b, const float* __restrict__ r1b,
    const float* __restrict__ c2b, const float* __restrict__ r2b,
    const float* __restrict__ d1wc, const float* __restrict__ d1bc,
    const float* __restrict__ d1wr, const float* __restrict__ d1br,
    const float* __restrict__ d2wc, const float* __restrict__ d2bc,
    const float* __restrict__ d2wr, const float* __restrict__ d2br,
    unsigned short* __restrict__ w1cat, unsigned short* __restrict__ w2cat,
    unsigned short* __restrict__ c3wb, unsigned short* __restrict__ wr3pad,
    float* __restrict__ br3pad, float* __restrict__ b1cat, float* __restrict__ b2cat,
    float* __restrict__ wd1, float* __restrict__ bd1,
    float* __restrict__ wd2, float* __restrict__ bd2) {
  int i = blockIdx.x * 256 + threadIdx.x;  // 262144
  {
    int which = i >> 16, j = i & 65535;
    float v = (which == 0) ? c1w[j] : (which == 1) ? r1w[j] : (which == 2) ? c2w[j] : r2w[j];
    unsigned short* dst = (which < 2) ? (w1cat + which * 65536) : (w2cat + (which - 2) * 65536);
    dst[j] = f2bf(v);
  }
  if (i < 32768) {
    int r = i >> 8, c = i & 255;
    wr3pad[i] = (r < 68) ? f2bf(r3w[r * 256 + c]) : (unsigned short)0;
    if (i < 128) br3pad[i] = (i < 68) ? r3b[i] : 0.f;
  }
  if (i < 256) c3wb[i] = f2bf(c3w[i]);
  if (i < 4608) {
    int tap = i >> 9, ch = i & 511, cc = ch & 255;
    wd1[i] = (ch < 256) ? d1wc[cc * 9 + tap] : d1wr[cc * 9 + tap];
    wd2[i] = (ch < 256) ? d2wc[cc * 9 + tap] : d2wr[cc * 9 + tap];
  }
  if (i < 512) {
    bd1[i] = (i < 256) ? d1bc[i] : d1br[i & 255];
    bd2[i] = (i < 256) ? d2bc[i] : d2br[i & 255];
    b1cat[i] = (i < 256) ? c1b[i] : r1b[i & 255];
    b2cat[i] = (i < 256) ? c2b[i] : r2b[i & 255];
  }
}

// ---------------- GEMM via global_load_lds, dbuf, counted vmcnt, swizzled LDS ----------
// Out[m,n] = A[m,:256] . W[n,:256] + bias[n].  A bf16 row-major (lda), W [N][256] bf16.
// grid.x = 1024 * nN (nN = 1<<lnN 128-col chunks), grid.z = branch (offsets).
__global__ __launch_bounds__(256, 3) void gemm_glds(
    const unsigned short* __restrict__ A, int lda, int zAoff,
    const unsigned short* __restrict__ W, int zWoff,
    const float* __restrict__ bias, int zBoff,
    unsigned short* __restrict__ Out, int ldo, int zOoff, int lnN) {
  __shared__ unsigned short lds[2][8192];   // [buf][ A: slots 0..511 | B: 512..1023 ] *8 shorts
  const int z = blockIdx.z;
  const unsigned short* Az = A + (long)z * zAoff;
  const unsigned short* Wz = W + (long)z * zWoff;
  const float* biasz = bias + z * zBoff;
  unsigned short* Outz = Out + (long)z * zOoff;

  // XCD-chunked bijective swizzle (gridDim.x divisible by 8)
  const int nwg = gridDim.x;
  const int bid = blockIdx.x;
  const int wg = (bid & 7) * (nwg >> 3) + (bid >> 3);
  const int mtile = wg >> lnN;
  const int ntile = wg & ((1 << lnN) - 1);
  const long row0 = (long)mtile * 128;
  const int col0 = ntile * 128;

  const int tid = threadIdx.x;
  const int lane = tid & 63;
  const int wid = tid >> 6;
  const int wr = (wid >> 1) * 64;
  const int wc = (wid & 1) * 64;
  const int rr = lane & 15;
  const int gk = lane >> 4;              // k-granule 0..3
  const int swz = (rr >> 1) & 3;         // read-side swizzle (row>>1)&3 == (rr>>1)&3

  // staging decomposition (per wave-call j): row = jj*64 + wid*16 + (lane>>2), gl = lane&3
  const int srow_l = (wid << 4) + (lane >> 2);
  const int sgl = lane & 3;

  f32x4 acc[4][4] = {};

  // ---- stage K-step into buf ----
  auto stage = [&](int buf, int k0) {
    #pragma unroll
    for (int j = 0; j < 4; j++) {
      const int slotbase = j * 256 + (wid << 6);
      unsigned short* ldst = &lds[buf][slotbase * 8];
      const int row = (j & 1) * 64 + srow_l;
      const int g = sgl ^ ((row >> 1) & 3);
      const unsigned short* src;
      if (j < 2) src = Az + (row0 + row) * (long)lda + k0 + g * 8;
      else       src = Wz + (long)(col0 + row) * 256 + k0 + g * 8;
      gload16(src, ldst);
    }
  };

  stage(0, 0);
  #pragma unroll
  for (int ks = 0; ks < 8; ks++) {
    if (ks < 7) {
      stage((ks + 1) & 1, (ks + 1) * 32);
      asm volatile("s_waitcnt vmcnt(4)" ::: "memory");
    } else {
      asm volatile("s_waitcnt vmcnt(0)" ::: "memory");
    }
    __builtin_amdgcn_s_barrier();
    asm volatile("" ::: "memory");
    const unsigned short* buf = lds[ks & 1];
    bf16x8 af[4], bf[4];
    #pragma unroll
    for (int mi = 0; mi < 4; mi++)
      af[mi] = __builtin_bit_cast(bf16x8,
          *(const uint4*)&buf[(wr + mi * 16 + rr) * 32 + ((gk ^ swz) * 8)]);
    #pragma unroll
    for (int ni = 0; ni < 4; ni++)
      bf[ni] = __builtin_bit_cast(bf16x8,
          *(const uint4*)&buf[4096 + (wc + ni * 16 + rr) * 32 + ((gk ^ swz) * 8)]);
    #pragma unroll
    for (int mi = 0; mi < 4; mi++)
      #pragma unroll
      for (int ni = 0; ni < 4; ni++)
        acc[mi][ni] = __builtin_amdgcn_mfma_f32_16x16x32_bf16(af[mi], bf[ni], acc[mi][ni], 0, 0, 0);
    asm volatile("" ::: "memory");
    __builtin_amdgcn_s_barrier();
  }

  #pragma unroll
  for (int mi = 0; mi < 4; mi++) {
    const int rbase = wr + mi * 16 + (lane >> 4) * 4;
    #pragma unroll
    for (int ni = 0; ni < 4; ni++) {
      const int c_ = wc + ni * 16 + (lane & 15);
      const float bv = biasz[col0 + c_];
      #pragma unroll
      for (int r = 0; r < 4; r++) {
        Outz[(row0 + rbase + r) * (long)ldo + col0 + c_] = f2bf(acc[mi][ni][r] + bv);
      }
    }
  }
}

// ---------------- depthwise 3x3 + bias + exact GELU, 2 pixels/thread ----------------
__global__ __launch_bounds__(256) void dwconv_gelu2(
    const unsigned short* __restrict__ In,
    const float* __restrict__ Wt, const float* __restrict__ Bt,
    unsigned short* __restrict__ Out) {
  int t = blockIdx.x * 256 + threadIdx.x;  // 65536 pairs * 64 groups
  int g = t & 63;
  int p = t >> 6;
  int n = p >> 11;
  int h = (p >> 5) & 63;
  int w0 = (p & 31) * 2;
  int cbase = g << 3;
  f32x2 accA[4], accB[4];
  {
    float4 b0 = *(const float4*)(Bt + cbase);
    float4 b1 = *(const float4*)(Bt + cbase + 4);
    accA[0].x = b0.x; accA[0].y = b0.y; accA[1].x = b0.z; accA[1].y = b0.w;
    accA[2].x = b1.x; accA[2].y = b1.y; accA[3].x = b1.z; accA[3].y = b1.w;
    #pragma unroll
    for (int i = 0; i < 4; i++) accB[i] = accA[i];
  }
  #pragma unroll
  for (int dy = -1; dy <= 1; dy++) {
    int hh = h + dy;
    if (hh < 0 || hh > 63) continue;
    const float* wb = Wt + ((dy + 1) * 3) * 512 + cbase;
    f32x2 wt0[4], wt1[4], wt2[4];
    {
      float4 a0 = *(const float4*)(wb);        float4 a1 = *(const float4*)(wb + 4);
      float4 b0 = *(const float4*)(wb + 512);  float4 b1 = *(const float4*)(wb + 516);
      float4 c0 = *(const float4*)(wb + 1024); float4 c1 = *(const float4*)(wb + 1028);
      wt0[0].x = a0.x; wt0[0].y = a0.y; wt0[1].x = a0.z; wt0[1].y = a0.w;
      wt0[2].x = a1.x; wt0[2].y = a1.y; wt0[3].x = a1.z; wt0[3].y = a1.w;
      wt1[0].x = b0.x; wt1[0].y = b0.y; wt1[1].x = b0.z; wt1[1].y = b0.w;
      wt1[2].x = b1.x; wt1[2].y = b1.y; wt1[3].x = b1.z; wt1[3].y = b1.w;
      wt2[0].x = c0.x; wt2[0].y = c0.y; wt2[1].x = c0.z; wt2[1].y = c0.w;
      wt2[2].x = c1.x; wt2[2].y = c1.y; wt2[3].x = c1.z; wt2[3].y = c1.w;
    }
    const long rowtok = (long)(((n << 6) + hh) << 6);
    if (w0 > 0) {
      uint4 v = *(const uint4*)(In + (rowtok + w0 - 1) * 512 + cbase);
      unsigned int u[4] = {v.x, v.y, v.z, v.w};
      #pragma unroll
      for (int i = 0; i < 4; i++) { f32x2 f = unpack2(u[i]); accA[i] += f * wt0[i]; }
    }
    {
      uint4 v = *(const uint4*)(In + (rowtok + w0) * 512 + cbase);
      unsigned int u[4] = {v.x, v.y, v.z, v.w};
      #pragma unroll
      for (int i = 0; i < 4; i++) { f32x2 f = unpack2(u[i]); accA[i] += f * wt1[i]; accB[i] += f * wt0[i]; }
    }
    {
      uint4 v = *(const uint4*)(In + (rowtok + w0 + 1) * 512 + cbase);
      unsigned int u[4] = {v.x, v.y, v.z, v.w};
      #pragma unroll
      for (int i = 0; i < 4; i++) { f32x2 f = unpack2(u[i]); accA[i] += f * wt2[i]; accB[i] += f * wt1[i]; }
    }
    if (w0 < 62) {
      uint4 v = *(const uint4*)(In + (rowtok + w0 + 2) * 512 + cbase);
      unsigned int u[4] = {v.x, v.y, v.z, v.w};
      #pragma unroll
      for (int i = 0; i < 4; i++) { f32x2 f = unpack2(u[i]); accB[i] += f * wt2[i]; }
    }
  }
  long mA = (long)(((n << 6) + h) << 6) + w0;
  __align__(16) unsigned short ov[8];
  #pragma unroll
  for (int i = 0; i < 4; i++) {
    f32x2 gA = gelu2(accA[i]);
    ov[2 * i] = f2bf(gA.x); ov[2 * i + 1] = f2bf(gA.y);
  }
  *(uint4*)(Out + mA * 512 + cbase) = *(uint4*)ov;
  #pragma unroll
  for (int i = 0; i < 4; i++) {
    f32x2 gB = gelu2(accB[i]);
    ov[2 * i] = f2bf(gB.x); ov[2 * i + 1] = f2bf(gB.y);
  }
  *(uint4*)(Out + (mA + 1) * 512 + cbase) = *(uint4*)ov;
}

// ---------------- cls fc3: dot(G2_c[m,:], w) + b ----------------
__global__ __launch_bounds__(256) void cls_dot(
    const unsigned short* __restrict__ G2,
    const unsigned short* __restrict__ Wc3,
    const float* __restrict__ bc3,
    float* __restrict__ cls_logit) {
  int lane = threadIdx.x & 63;
  int wid = threadIdx.x >> 6;
  long m = (long)blockIdx.x * 4 + wid;
  const unsigned short* row = G2 + m * 512;
  ushort4 a = *(const ushort4*)(row + lane * 4);
  ushort4 wv = *(const ushort4*)(Wc3 + lane * 4);
  float s = bf2f(a.x) * bf2f(wv.x) + bf2f(a.y) * bf2f(wv.y) +
            bf2f(a.z) * bf2f(wv.z) + bf2f(a.w) * bf2f(wv.w);
  #pragma unroll
  for (int off = 32; off > 0; off >>= 1) s += __shfl_down(s, off);
  if (lane == 0) cls_logit[m] = s + bc3[0];
}

// ---------------- post: softmax-17, boxes, top4, q-net, cls fuse ----------------
__global__ __launch_bounds__(256) void post_kernel(
    const unsigned short* __restrict__ RP,
    const float* __restrict__ cls_logit,
    const float* __restrict__ rc1_w, const float* __restrict__ rc1_b,
    const float* __restrict__ rc2_w, const float* __restrict__ rc2_b,
    float* __restrict__ out_cls, float* __restrict__ out_boxes, float* __restrict__ out_reg) {
  int m = blockIdx.x * 256 + threadIdx.x;
  const unsigned short* rp = RP + (long)m * 128;
  float stat[20];
  #pragma unroll
  for (int s = 0; s < 4; s++) {
    float v[17];
    float mx = -1e30f;
    #pragma unroll
    for (int i = 0; i < 17; i++) {
      v[i] = bf2f(rp[s * 17 + i]);
      out_reg[(long)m * 68 + s * 17 + i] = v[i];
      mx = fmaxf(mx, v[i]);
    }
    float sum = 0.f;
    #pragma unroll
    for (int i = 0; i < 17; i++) { v[i] = __expf(v[i] - mx); sum += v[i]; }
    float inv = 1.f / sum;
    float dist = 0.f;
    #pragma unroll
    for (int i = 0; i < 17; i++) { v[i] *= inv; dist += v[i] * (float)i; }
    out_boxes[(long)m * 4 + s] = dist * 0.0625f;
    float tk[4];
    #pragma unroll
    for (int t = 0; t < 4; t++) {
      float bm = v[0]; int bi = 0;
      #pragma unroll
      for (int i = 1; i < 17; i++) {
        if (v[i] > bm) { bm = v[i]; bi = i; }
      }
      tk[t] = bm;
      #pragma unroll
      for (int i = 0; i < 17; i++)
        if (i == bi) v[i] = -1.f;
    }
    stat[s * 5 + 0] = tk[0]; stat[s * 5 + 1] = tk[1];
    stat[s * 5 + 2] = tk[2]; stat[s * 5 + 3] = tk[3];
    stat[s * 5 + 4] = 0.25f * (tk[0] + tk[1] + tk[2] + tk[3]);
  }
  float z = 0.f;
  #pragma unroll
  for (int o = 0; o < 64; o++) {
    float q = rc1_b[o];
    #pragma unroll
    for (int c = 0; c < 20; c++) q += rc1_w[o * 20 + c] * stat[c];
    q = fmaxf(q, 0.f);
    z += q * rc2_w[o];
  }
  z += rc2_b[0];
  float q2 = 1.f / (1.f + __expf(-z));
  float cl = 1.f / (1.f + __expf(-cls_logit[m]));
  out_cls[m] = cl * q2;
}

extern "C" void kernel_launch(void* const* d_in, const int* in_sizes, int n_in,
                              void* d_out, int out_size, void* d_ws, size_t ws_size,
                              hipStream_t stream) {
  const float* x       = (const float*)d_in[0];
  const float* c_fc1_w = (const float*)d_in[1];
  const float* c_fc1_b = (const float*)d_in[2];
  const float* c_dw1_w = (const float*)d_in[3];
  const float* c_dw1_b = (const float*)d_in[4];
  const float* c_fc2_w = (const float*)d_in[5];
  const float* c_fc2_b = (const float*)d_in[6];
  const float* c_dw2_w = (const float*)d_in[7];
  const float* c_dw2_b = (const float*)d_in[8];
  const float* c_fc3_w = (const float*)d_in[9];
  const float* c_fc3_b = (const float*)d_in[10];
  const float* r_fc1_w = (const float*)d_in[11];
  const float* r_fc1_b = (const float*)d_in[12];
  const float* r_dw1_w = (const float*)d_in[13];
  const float* r_dw1_b = (const float*)d_in[14];
  const float* r_fc2_w = (const float*)d_in[15];
  const float* r_fc2_b = (const float*)d_in[16];
  const float* r_dw2_w = (const float*)d_in[17];
  const float* r_dw2_b = (const float*)d_in[18];
  const float* r_fc3_w = (const float*)d_in[19];
  const float* r_fc3_b = (const float*)d_in[20];
  const float* rc1_w   = (const float*)d_in[21];
  const float* rc1_b   = (const float*)d_in[22];
  const float* rc2_w   = (const float*)d_in[23];
  const float* rc2_b   = (const float*)d_in[24];

  char* ws = (char*)d_ws;
  unsigned short* Hbuf = (unsigned short*)ws;                       // 128 MiB
  unsigned short* Gbuf = (unsigned short*)(ws + 134217728L);        // 128 MiB
  unsigned short* xb   = Gbuf;                                      // 64 MiB alias (dead after fc1)
  unsigned short* RP   = (unsigned short*)(ws + 268435456L);        // 32 MiB
  float* cls_logit     = (float*)(ws + 301989888L);                 // 512 KiB
  char* wb             = ws + 302514176L;
  unsigned short* w1cat  = (unsigned short*)wb;          // 131072 bf16 (c_fc1|r_fc1)
  unsigned short* w2cat  = w1cat + 131072;               // 131072 bf16 (c_fc2|r_fc2)
  unsigned short* c3wb   = w2cat + 131072;               // 256
  unsigned short* wr3pad = c3wb + 256;                   // 32768
  float* br3pad = (float*)(wr3pad + 32768);              // 128
  float* b1cat  = br3pad + 128;                          // 512
  float* b2cat  = b1cat + 512;                           // 512
  float* wd1    = b2cat + 512;                           // 4608
  float* bd1    = wd1 + 4608;                            // 512
  float* wd2    = bd1 + 512;                             // 4608
  float* bd2    = wd2 + 4608;                            // 512

  prep_all<<<1024, 256, 0, stream>>>(
      c_fc1_w, r_fc1_w, c_fc2_w, r_fc2_w, c_fc3_w, r_fc3_w, r_fc3_b,
      c_fc1_b, r_fc1_b, c_fc2_b, r_fc2_b,
      c_dw1_w, c_dw1_b, r_dw1_w, r_dw1_b,
      c_dw2_w, c_dw2_b, r_dw2_w, r_dw2_b,
      w1cat, w2cat, c3wb, wr3pad, br3pad, b1cat, b2cat,
      wd1, bd1, wd2, bd2);
  cvt_x<<<16384, 256, 0, stream>>>(x, xb);

  // fc1: A = xb (bf16, lda 256), N=512 (nN=4)
  gemm_glds<<<dim3(4096, 1, 1), 256, 0, stream>>>(
      xb, 256, 0, w1cat, 0, b1cat, 0, Hbuf, 512, 0, 2);
  // dwconv1 + gelu
  dwconv_gelu2<<<16384, 256, 0, stream>>>(Hbuf, wd1, bd1, Gbuf);
  // fc2: branches via z (nN=2 per branch)
  gemm_glds<<<dim3(2048, 1, 2), 256, 0, stream>>>(
      Gbuf, 512, 256, w2cat, 65536, b2cat, 256, Hbuf, 512, 256, 1);
  // dwconv2 + gelu
  dwconv_gelu2<<<16384, 256, 0, stream>>>(Hbuf, wd2, bd2, Gbuf);
  // fc3
  cls_dot<<<32768, 256, 0, stream>>>(Gbuf, c3wb, c_fc3_b, cls_logit);
  gemm_glds<<<dim3(1024, 1, 1), 256, 0, stream>>>(
      Gbuf + 256, 512, 0, wr3pad, 0, br3pad, 0, RP, 128, 0, 0);
  // post
  float* out_cls   = (float*)d_out;
  float* out_boxes = out_cls + 131072;
  float* out_reg   = out_boxes + 524288;
  post_kernel<<<512, 256, 0, stream>>>(RP, cls_logit, rc1_w, rc1_b, rc2_w, rc2_b,
                                       out_cls, out_boxes, out_reg);
}